// Round 1
// baseline (178.688 us; speedup 1.0000x reference)
//
#include <hip/hip_runtime.h>

#define NBLK 256

// tanh(x) = 1 - 2/(exp(2x)+1).  exp overflow -> inf -> rcp=0 -> +1; underflow -> -1.
// abs error ~3e-7 (v_exp_f32 + v_rcp_f32), well inside the 1.69e-3 absmax budget.
__device__ __forceinline__ float fast_tanh(float x) {
    float e = __expf(2.0f * x);
    return 1.0f - 2.0f * __builtin_amdgcn_rcpf(e + 1.0f);
}

__global__ __launch_bounds__(NBLK) void pinn_kernel(
    const float* __restrict__ T,
    const float* __restrict__ W1, const float* __restrict__ b1,
    const float* __restrict__ W2, const float* __restrict__ b2,
    const float* __restrict__ W3, const float* __restrict__ b3,
    const float* __restrict__ W4, const float* __restrict__ b4,
    const float* __restrict__ Wo, const float* __restrict__ bo,
    const float* __restrict__ C1, const float* __restrict__ C2, const float* __restrict__ C3,
    float* __restrict__ out, int n)
{
    // W2,W3,W4 concatenated so the layer loop indexes one LDS array (keeps addrspace(3)).
    __shared__ __align__(16) float sW[1200];   // [L][20][20], row-major per layer
    __shared__ __align__(16) float sB[64];     // b2,b3,b4 (60 used)
    __shared__ __align__(16) float sW1[20];
    __shared__ __align__(16) float sb1[20];
    __shared__ __align__(16) float sWoT[64];   // transposed Wo: [3][20] (60 used)
    __shared__ float sbo[4];

    const int tid = threadIdx.x;
    for (int i2 = tid; i2 < 400; i2 += NBLK) {
        sW[i2]       = W2[i2];
        sW[400 + i2] = W3[i2];
        sW[800 + i2] = W4[i2];
    }
    if (tid < 20) {
        sW1[tid] = W1[tid];
        sb1[tid] = b1[tid];
        sB[tid]      = b2[tid];
        sB[20 + tid] = b3[tid];
        sB[40 + tid] = b4[tid];
    }
    if (tid < 60) sWoT[(tid % 3) * 20 + (tid / 3)] = Wo[tid];  // sWoT[j*20+k] = Wo[k*3+j]
    if (tid < 3)  sbo[tid] = bo[tid];
    __syncthreads();

    const int i = blockIdx.x * NBLK + tid;
    if (i >= n) return;

    const float t = T[i];

    float h[20], dh[20];

    // ---- layer 1: z = t*W1 + b1, dz = W1 (tangent dt = 1) ----
#pragma unroll
    for (int j = 0; j < 20; j += 4) {
        const float4 w = *reinterpret_cast<const float4*>(sW1 + j);
        const float4 b = *reinterpret_cast<const float4*>(sb1 + j);
        float zz[4] = { t * w.x + b.x, t * w.y + b.y, t * w.z + b.z, t * w.w + b.w };
        float dz[4] = { w.x, w.y, w.z, w.w };
#pragma unroll
        for (int q = 0; q < 4; ++q) {
            float e = fast_tanh(zz[q]);
            h[j + q]  = e;
            dh[j + q] = (1.0f - e * e) * dz[q];
        }
    }

    // ---- layers 2..4 (shared code body; L-loop kept rolled for i-cache) ----
#pragma unroll 1
    for (int L = 0; L < 3; ++L) {
        const float* __restrict__ w  = sW + L * 400;
        const float* __restrict__ bb = sB + L * 20;
        float nh[20], ndh[20];
#pragma unroll
        for (int j = 0; j < 20; j += 4) {
            float a0 = bb[j], a1 = bb[j + 1], a2 = bb[j + 2], a3 = bb[j + 3];
            float d0 = 0.f, d1 = 0.f, d2 = 0.f, d3 = 0.f;
#pragma unroll
            for (int k = 0; k < 20; ++k) {
                const float4 ww = *reinterpret_cast<const float4*>(w + k * 20 + j);
                const float hk = h[k], dk = dh[k];
                a0 += hk * ww.x; a1 += hk * ww.y; a2 += hk * ww.z; a3 += hk * ww.w;
                d0 += dk * ww.x; d1 += dk * ww.y; d2 += dk * ww.z; d3 += dk * ww.w;
            }
            float e0 = fast_tanh(a0), e1 = fast_tanh(a1), e2 = fast_tanh(a2), e3 = fast_tanh(a3);
            nh[j] = e0; nh[j + 1] = e1; nh[j + 2] = e2; nh[j + 3] = e3;
            ndh[j]     = (1.0f - e0 * e0) * d0;
            ndh[j + 1] = (1.0f - e1 * e1) * d1;
            ndh[j + 2] = (1.0f - e2 * e2) * d2;
            ndh[j + 3] = (1.0f - e3 * e3) * d3;
        }
#pragma unroll
        for (int j = 0; j < 20; ++j) { h[j] = nh[j]; dh[j] = ndh[j]; }
    }

    // ---- output layer: out = h@Wo + bo, dout = dh@Wo (via transposed Wo) ----
    float o[3], dO[3];
#pragma unroll
    for (int j = 0; j < 3; ++j) {
        float a = sbo[j], d = 0.f;
#pragma unroll
        for (int k = 0; k < 20; k += 4) {
            const float4 ww = *reinterpret_cast<const float4*>(sWoT + j * 20 + k);
            a += h[k] * ww.x + h[k + 1] * ww.y + h[k + 2] * ww.z + h[k + 3] * ww.w;
            d += dh[k] * ww.x + dh[k + 1] * ww.y + dh[k + 2] * ww.z + dh[k + 3] * ww.w;
        }
        o[j] = a; dO[j] = d;
    }

    const float x = o[0], y = o[1], zz = o[2];
    const float dx = dO[0], dy = dO[1], dz = dO[2];
    const float c1 = C1[0], c2 = C2[0], c3 = C3[0];

    const float fx = dx - c1 * (y - x);
    const float fy = dy - x * (c2 - zz) + y;
    const float fz = dz - x * y + c3 * zz;

    // out[i*6 + {0..5}] = x,y,z,fx,fy,fz ; 24*i bytes is always 8B-aligned -> float2 stores
    float2* po = reinterpret_cast<float2*>(out + (size_t)i * 6);
    po[0] = make_float2(x,  y);
    po[1] = make_float2(zz, fx);
    po[2] = make_float2(fy, fz);
}

extern "C" void kernel_launch(void* const* d_in, const int* in_sizes, int n_in,
                              void* d_out, int out_size, void* d_ws, size_t ws_size,
                              hipStream_t stream) {
    const float* T  = (const float*)d_in[0];
    const float* W1 = (const float*)d_in[1];
    const float* b1 = (const float*)d_in[2];
    const float* W2 = (const float*)d_in[3];
    const float* b2 = (const float*)d_in[4];
    const float* W3 = (const float*)d_in[5];
    const float* b3 = (const float*)d_in[6];
    const float* W4 = (const float*)d_in[7];
    const float* b4 = (const float*)d_in[8];
    const float* Wo = (const float*)d_in[9];
    const float* bo = (const float*)d_in[10];
    const float* C1 = (const float*)d_in[11];
    const float* C2 = (const float*)d_in[12];
    const float* C3 = (const float*)d_in[13];
    float* out = (float*)d_out;

    const int n = in_sizes[0];
    const int blocks = (n + NBLK - 1) / NBLK;
    pinn_kernel<<<blocks, NBLK, 0, stream>>>(T, W1, b1, W2, b2, W3, b3, W4, b4,
                                             Wo, bo, C1, C2, C3, out, n);
}